// Round 16
// baseline (129.049 us; speedup 1.0000x reference)
//
#include <hip/hip_runtime.h>
#include <hip/hip_bf16.h>
#include <cstdint>

using short8  = __attribute__((ext_vector_type(8))) short;
using u16x8   = __attribute__((ext_vector_type(8))) unsigned short;
using u16x4   = __attribute__((ext_vector_type(4))) unsigned short;
using f32x4   = __attribute__((ext_vector_type(4))) float;
using f32x16  = __attribute__((ext_vector_type(16))) float;

constexpr int BN = 4, HN = 4, SN = 4096, DN = 256, HD = 64;
constexpr int MROWS = BN * SN;  // 16384
// Q pre-scale: (1/sqrt(64)) * log2(e) -> scores land in exp2 domain
constexpr float QSCL = 0.18033688011112042f;

__device__ __forceinline__ unsigned short f2bf(float x) {
  union { float f; unsigned int u; } c; c.f = x;
  unsigned int u = c.u;
  return (unsigned short)((u + 0x7fffu + ((u >> 16) & 1u)) >> 16);
}
__device__ __forceinline__ unsigned int cvt_pk_bf16(float a, float b) {
  unsigned int r;
  asm("v_cvt_pk_bf16_f32 %0, %1, %2" : "=v"(r) : "v"(a), "v"(b));
  return r;  // low16 = bf16(a), high16 = bf16(b)
}
// proven-correct since round 5: operands are distinct values produced by
// cvt_pk several instructions before the swap (hazard-safe by distance).
__device__ __forceinline__ void pl32swap(unsigned int& a, unsigned int& b) {
  asm volatile("v_permlane32_swap_b32 %0, %1" : "+v"(a), "+v"(b));
}

#define GLDS16(g, l)                                                  \
  __builtin_amdgcn_global_load_lds(                                   \
      (const __attribute__((address_space(1))) void*)(g),             \
      (__attribute__((address_space(3))) void*)(l), 16, 0, 0)

// ---------------- fp32 -> bf16 conversion: x, Wq|Wk|Wv (concat), Wo
__global__ __launch_bounds__(256) void convert_kernel(
    const float* __restrict__ x,  const float* __restrict__ Wq,
    const float* __restrict__ Wk, const float* __restrict__ Wv,
    const float* __restrict__ Wo,
    unsigned short* __restrict__ xb, unsigned short* __restrict__ Wcat,
    unsigned short* __restrict__ Wob) {
  const long NX4 = (long)MROWS * DN / 4;
  const long NW4 = 65536 / 4;
  const long total = NX4 + 4 * NW4;
  for (long i = (long)blockIdx.x * 256 + threadIdx.x; i < total;
       i += (long)gridDim.x * 256) {
    const float* src; unsigned short* dst;
    if (i < NX4) { src = x + i * 4; dst = xb + i * 4; }
    else {
      long j = i - NX4; int w = (int)(j >> 14); long o = (j & 16383) * 4;
      src = (w == 0 ? Wq : w == 1 ? Wk : w == 2 ? Wv : Wo) + o;
      dst = (w < 3 ? Wcat + (long)w * 65536 : Wob) + o;
    }
    float4 v = *(const float4*)src;
    u16x4 pk; pk[0] = f2bf(v.x); pk[1] = f2bf(v.y);
    pk[2] = f2bf(v.z); pk[3] = f2bf(v.w);
    *(u16x4*)dst = pk;
  }
}

// ---------------- bf16 MFMA GEMM: C[M][N] = A[M][K=256] * B[N][K=256]^T
// MODE 0: write q(*QSCL)/k bf16 [B,H,S,HD]; V transposed as [B,H,HD,S].
// MODE 1: write fp32 [M][256].
template <int MODE, int NBN>
__global__ __launch_bounds__(256) void gemm_kernel(
    const unsigned short* __restrict__ Abf,
    const unsigned short* __restrict__ Bbf,
    unsigned short* __restrict__ qo, unsigned short* __restrict__ ko,
    unsigned short* __restrict__ vo, float* __restrict__ out) {
  constexpr int SMEM = (MODE == 1) ? 128 * 132 * 4 : 128 * 136 * 2;
  __shared__ __align__(16) char smem[SMEM];
  unsigned short* stg = (unsigned short*)smem;

  const int tid = threadIdx.x, lane = tid & 63, wid = tid >> 6;
  const int lo = lane & 15, hi = lane >> 4;
  const int bn = blockIdx.x % NBN, bm = blockIdx.x / NBN;
  const int wm = (wid >> 1) * 64, wn = (wid & 1) * 64;
  const long arow0 = (long)bm * 128, brow0 = (long)bn * 128;

  auto stage = [&](int buf, int kt) {
    const int row = (wid * 2) * 16 + (lane >> 2);
    const int col = (lane & 3) * 8;
    const unsigned short* ga = Abf + (arow0 + row) * DN + kt * 32 + col;
    const unsigned short* gb = Bbf + (brow0 + row) * DN + kt * 32 + col;
    unsigned short* la = stg + buf * 8192 + wid * 1024;
    unsigned short* lb = la + 4096;
    GLDS16(ga, la);
    GLDS16(ga + 16 * DN, la + 512);
    GLDS16(gb, lb);
    GLDS16(gb + 16 * DN, lb + 512);
  };

  f32x4 acc[4][4];
#pragma unroll
  for (int a = 0; a < 4; ++a)
#pragma unroll
    for (int b = 0; b < 4; ++b)
#pragma unroll
      for (int e = 0; e < 4; ++e) acc[a][b][e] = 0.f;

  stage(0, 0);
#pragma unroll
  for (int kt = 0; kt < 8; ++kt) {
    const int buf = kt & 1;
    __syncthreads();
    if (kt < 7) stage(buf ^ 1, kt + 1);
    const unsigned short* sa = stg + buf * 8192;
    const unsigned short* sb = sa + 4096;
    short8 af[4], bf[4];
#pragma unroll
    for (int f = 0; f < 4; ++f) {
      af[f] = *(const short8*)(sa + (wm + f * 16 + lo) * 32 + hi * 8);
      bf[f] = *(const short8*)(sb + (wn + f * 16 + lo) * 32 + hi * 8);
    }
#pragma unroll
    for (int fn = 0; fn < 4; ++fn)
#pragma unroll
      for (int fm = 0; fm < 4; ++fm)
        acc[fn][fm] = __builtin_amdgcn_mfma_f32_16x16x32_bf16(
            bf[fn], af[fm], acc[fn][fm], 0, 0, 0);
  }
  __syncthreads();

  if constexpr (MODE == 0) {
    unsigned short* cs = (unsigned short*)smem;
    if (bn < 4) {  // Q and K: [B,H,S,HD]
      const float cscl = (bn < 2) ? QSCL : 1.0f;
#pragma unroll
      for (int fn = 0; fn < 4; ++fn)
#pragma unroll
        for (int fm = 0; fm < 4; ++fm) {
          u16x4 pk;
#pragma unroll
          for (int r = 0; r < 4; ++r) pk[r] = f2bf(acc[fn][fm][r] * cscl);
          const int m = wm + fm * 16 + lo, n0 = wn + fn * 16 + hi * 4;
          *(u16x4*)(cs + m * 136 + n0) = pk;
        }
      __syncthreads();
      unsigned short* dstmat = (bn < 2) ? qo : ko;
      const int colbase = (bn & 1) * 128;
#pragma unroll
      for (int p = 0; p < 8; ++p) {
        const int ml = p * 16 + (tid >> 4), n0 = (tid & 15) * 8;
        u16x8 v = *(u16x8*)(cs + ml * 136 + n0);
        const int c = colbase + n0, h = c >> 6, hd = c & 63;
        const long m = arow0 + ml;
        const int b = (int)(m >> 12), s = (int)(m & 4095);
        *(u16x8*)(dstmat + ((long)(b * HN + h) * SN + s) * HD + hd) = v;
      }
    } else {  // V: store cs transposed, write V^T [B,H,HD,S]
#pragma unroll
      for (int fn = 0; fn < 4; ++fn)
#pragma unroll
        for (int fm = 0; fm < 4; ++fm) {
          const int m = wm + fm * 16 + lo, n0 = wn + fn * 16 + hi * 4;
#pragma unroll
          for (int r = 0; r < 4; ++r)
            cs[(n0 + r) * 136 + m] = f2bf(acc[fn][fm][r]);
        }
      __syncthreads();
      const int b = (int)(arow0 >> 12), sbase = (int)(arow0 & 4095);
#pragma unroll
      for (int p = 0; p < 8; ++p) {
        const int cl = p * 16 + (tid >> 4);   // local col (head-dim axis)
        const int s0 = (tid & 15) * 8;        // s offset within tile
        u16x8 v = *(u16x8*)(cs + cl * 136 + s0);
        const int c = (bn & 1) * 128 + cl, h = c >> 6, hd = c & 63;
        *(u16x8*)(vo + ((long)((b * HN + h) * HD + hd)) * SN + sbase + s0) = v;
      }
    }
  } else {
    float* csf = (float*)smem;
#pragma unroll
    for (int fn = 0; fn < 4; ++fn)
#pragma unroll
      for (int fm = 0; fm < 4; ++fm) {
        const int m = wm + fm * 16 + lo, n0 = wn + fn * 16 + hi * 4;
        *(f32x4*)(csf + m * 132 + n0) = acc[fn][fm];
      }
    __syncthreads();
#pragma unroll
    for (int p = 0; p < 8; ++p) {
      const int ml = p * 16 + (tid >> 4), n0 = (tid & 15) * 8;
      f32x4 v0 = *(f32x4*)(csf + ml * 132 + n0);
      f32x4 v1 = *(f32x4*)(csf + ml * 132 + n0 + 4);
      float* dst = out + (arow0 + ml) * DN + bn * 128 + n0;
      *(f32x4*)dst = v0;
      *(f32x4*)(dst + 4) = v1;
    }
  }
}

// ---------------- flash attention, causal. 8-warp blocks, 256 q rows
// (warp w owns q [q0+32w, q0+32w+32)). One K tile [64key][64hd] + V^T tile
// [64hd][64key] staged to LDS serves all 8 warps (2x less staging per unit
// work than 4-warp blocks) -- LDS stays 32 KB/block, so 2 blocks/CU = 16
// waves/CU (double round-13's 8; r15 showed occupancy was the limiter and
// is LDS-bound, not VGPR-bound). 16B XOR swizzle as inverse-swizzled
// global source + swizzled LDS reads. 2-phase pipeline (m97 shape).
// Complementary t-order pairs heavy/light blocks across the CU assignment.
// NSPLIT=2: kt parity split, fp32 partials + merge kernel.
template <int NSPLIT>
__global__ __launch_bounds__(512, 4) void attn_kernel(
    const unsigned short* __restrict__ Qw, const unsigned short* __restrict__ Kw,
    const unsigned short* __restrict__ VTp, unsigned short* __restrict__ Ow,
    float* __restrict__ Op, float* __restrict__ Mp, float* __restrict__ Lp) {
  // sMem[buf][0..4095] = K tile [key][hd] swz; [4096..8191] = V^T [hd][key]
  __shared__ __align__(16) unsigned short sMem[2][8192];

  const int tid = threadIdx.x;
  const int w = tid >> 6, lane = tid & 63;
  const int l31 = lane & 31, h5 = lane >> 5;
  const int bid = blockIdx.x;
  const int bh = (bid & 7) * 2 + ((bid >> 3) & 1);  // 2 bh per XCD
  int c, g;
  if constexpr (NSPLIT == 2) { c = (bid >> 4) & 1; g = bid >> 5; }
  else { c = 0; g = bid >> 4; }
  const int t = (g < 8) ? (15 - g) : (g - 8);  // heavy/light complementary
  const int q0 = t * 256;
  const int qw = q0 + w * 32;
  const long base = (long)bh * SN * HD;    // == bh * HD * SN for V^T too
  const int tlast = 4 * t + 3;             // last kt tile for the block
  const int wlast = 4 * t + (w >> 1);      // this warp's last active tile

  // staging: 16 issues of 1KB cover K(8KB)+V(8KB); warp w does 1 K + 1 V.
  const int sr = w * 8 + (lane >> 3);           // row of this lane
  const int gcol8 = (((lane & 7) ^ (lane >> 3)) << 3);  // inv-swizzled chunk
  auto stage = [&](int buf, int k0) {
    const unsigned short* gk = Kw + base + (long)(k0 + sr) * HD + gcol8;
    GLDS16(gk, &sMem[buf][w * 512]);
    const unsigned short* gv = VTp + base + (long)sr * SN + k0 + gcol8;
    GLDS16(gv, &sMem[buf][4096 + w * 512]);
  };

  // Q frags (B-operand): lane holds Q[qw+l31][16ks + 8*h5 + j], pre-scaled
  short8 qf[4];
#pragma unroll
  for (int ks = 0; ks < 4; ++ks)
    qf[ks] = *(const short8*)(Qw + base + (long)(qw + l31) * HD + ks * 16 + h5 * 8);

  f32x16 oacc[2];  // [oh]: O[hd=32*oh+crow(r,h5)][q=l31]
  f32x16 zro;      // persistent zero C-operand (saves 32 movs/tile)
#pragma unroll
  for (int r = 0; r < 16; ++r) zro[r] = 0.f;
  oacc[0] = zro; oacc[1] = zro;
  float m_ = -INFINITY, l_ = 0.f;  // per-lane softmax state for q = qw+l31

  const int swz = (l31 & 7) << 3;  // read-side swizzle (ushort units /8)

  stage(0, c * 64);
  __syncthreads();  // drain prologue stage before first ds_read (r13 fix)
  int buf = 0;
  for (int kt = c; kt <= tlast; kt += NSPLIT) {
    if (kt + NSPLIT <= tlast) stage(buf ^ 1, (kt + NSPLIT) * 64);

    if (kt <= wlast) {
      const int k0 = kt * 64;
      const unsigned short* sK = &sMem[buf][0];
      const unsigned short* sV = &sMem[buf][4096];
      // ---- K frags from LDS (swizzled b128)
      short8 kb[8];
#pragma unroll
      for (int s = 0; s < 2; ++s)
#pragma unroll
        for (int ks = 0; ks < 4; ++ks)
          kb[s * 4 + ks] = *(const short8*)&sK[(32 * s + l31) * 64 +
                                              (((2 * ks + h5) << 3) ^ swz)];
      // ---- QK^T: C[key=32s+crow(r,h5)][q=l31], log2 domain
      f32x16 c0, c1;
      c0 = __builtin_amdgcn_mfma_f32_32x32x16_bf16(kb[0], qf[0], zro, 0, 0, 0);
      c1 = __builtin_amdgcn_mfma_f32_32x32x16_bf16(kb[4], qf[0], zro, 0, 0, 0);
#pragma unroll
      for (int ks = 1; ks < 4; ++ks)
        c0 = __builtin_amdgcn_mfma_f32_32x32x16_bf16(kb[ks], qf[ks], c0, 0, 0, 0);
#pragma unroll
      for (int ks = 1; ks < 4; ++ks)
        c1 = __builtin_amdgcn_mfma_f32_32x32x16_bf16(kb[4 + ks], qf[ks], c1, 0, 0, 0);

      // ---- V^T frags from LDS; latency hides under softmax below
      short8 vt0[4], vt1[4];
#pragma unroll
      for (int ks = 0; ks < 4; ++ks) {
        const int col = ((2 * ks + h5) << 3) ^ swz;
        vt0[ks] = *(const short8*)&sV[l31 * 64 + col];
        vt1[ks] = *(const short8*)&sV[(32 + l31) * 64 + col];
      }

      // ---- causal mask (only this warp's diagonal tile)
      if (kt == wlast) {
        const int mb0 = k0 + 4 * h5 - qw - l31;  // key - q for s=0, r=0
#pragma unroll
        for (int r = 0; r < 16; ++r) {
          const int d = (r & 3) + 8 * (r >> 2);
          if (mb0 + d > 0)      c0[r] = -INFINITY;
          if (mb0 + 32 + d > 0) c1[r] = -INFINITY;
        }
      }

      // ---- row max: in-reg tree + shfl cross-half
      float mv[16];
#pragma unroll
      for (int r = 0; r < 16; ++r) mv[r] = fmaxf(c0[r], c1[r]);
#pragma unroll
      for (int st = 8; st >= 1; st >>= 1)
#pragma unroll
        for (int i = 0; i < st; ++i) mv[i] = fmaxf(mv[i], mv[i + st]);
      const float mx = fmaxf(mv[0], __shfl_xor(mv[0], 32, 64));

      // ---- defer-max (T13): rescale only when max grew materially
      if (__any(mx > m_ + 11.5f)) {
        const float mn = fmaxf(m_, mx);
        const float alpha = __builtin_amdgcn_exp2f(m_ - mn);
        m_ = mn;
        l_ *= alpha;
#pragma unroll
        for (int oh = 0; oh < 2; ++oh)
#pragma unroll
          for (int r = 0; r < 16; ++r) oacc[oh][r] *= alpha;
      }

      // ---- exp2 + row sum
#pragma unroll
      for (int r = 0; r < 16; ++r) {
        c0[r] = __builtin_amdgcn_exp2f(c0[r] - m_);
        c1[r] = __builtin_amdgcn_exp2f(c1[r] - m_);
      }
      float sv[16];
#pragma unroll
      for (int r = 0; r < 16; ++r) sv[r] = c0[r] + c1[r];
#pragma unroll
      for (int st = 8; st >= 1; st >>= 1)
#pragma unroll
        for (int i = 0; i < st; ++i) sv[i] += sv[i + st];
      l_ += sv[0] + __shfl_xor(sv[0], 32, 64);

      // ---- P (B-operand) in-register via cvt_pk + permlane32_swap (T12)
      short8 pb[4];
#pragma unroll
      for (int s = 0; s < 2; ++s)
#pragma unroll
        for (int u = 0; u < 2; ++u) {
          unsigned int a0, a1, b0, b1;
          if (s == 0) {
            a0 = cvt_pk_bf16(c0[8 * u + 0], c0[8 * u + 1]);
            a1 = cvt_pk_bf16(c0[8 * u + 2], c0[8 * u + 3]);
            b0 = cvt_pk_bf16(c0[8 * u + 4], c0[8 * u + 5]);
            b1 = cvt_pk_bf16(c0[8 * u + 6], c0[8 * u + 7]);
          } else {
            a0 = cvt_pk_bf16(c1[8 * u + 0], c1[8 * u + 1]);
            a1 = cvt_pk_bf16(c1[8 * u + 2], c1[8 * u + 3]);
            b0 = cvt_pk_bf16(c1[8 * u + 4], c1[8 * u + 5]);
            b1 = cvt_pk_bf16(c1[8 * u + 6], c1[8 * u + 7]);
          }
          pl32swap(a0, b0);
          pl32swap(a1, b1);
          union { unsigned int u4[4]; short8 v; } pu;
          pu.u4[0] = a0; pu.u4[1] = a1; pu.u4[2] = b0; pu.u4[3] = b1;
          pb[s * 2 + u] = pu.v;
        }

      // ---- PV: oacc[oh] += V^T * P
#pragma unroll
      for (int ks = 0; ks < 4; ++ks) {
        oacc[0] = __builtin_amdgcn_mfma_f32_32x32x16_bf16(vt0[ks], pb[ks], oacc[0], 0, 0, 0);
        oacc[1] = __builtin_amdgcn_mfma_f32_32x32x16_bf16(vt1[ks], pb[ks], oacc[1], 0, 0, 0);
      }
    }

    __syncthreads();  // drains this iter's staged loads; fences buf reuse
    buf ^= 1;
  }

  if constexpr (NSPLIT == 1) {
    // ---- epilogue: transpose O through LDS (reuse sMem), coalesced store
    unsigned short* ob = &sMem[0][0];  // 8 warps x [32 q][64 hd] = 32 KB
    const float rl = 1.f / l_;
#pragma unroll
    for (int oh = 0; oh < 2; ++oh)
#pragma unroll
      for (int rq = 0; rq < 4; ++rq) {
        const int hdb = 32 * oh + 8 * rq + 4 * h5;
        const unsigned int u0 = cvt_pk_bf16(oacc[oh][4 * rq + 0] * rl,
                                            oacc[oh][4 * rq + 1] * rl);
        const unsigned int u1 = cvt_pk_bf16(oacc[oh][4 * rq + 2] * rl,
                                            oacc[oh][4 * rq + 3] * rl);
        *(uint2*)&ob[w * 2048 + l31 * 64 + (hdb ^ ((l31 & 7) << 3))] =
            make_uint2(u0, u1);
      }
    __syncthreads();
    const int b = bh >> 2, h = bh & 3;
#pragma unroll
    for (int pass = 0; pass < 4; ++pass) {
      const int idx = pass * 512 + tid;
      const int row = idx >> 3, j = idx & 7;    // row 0..255, 8 ushorts
      const int wreg = row >> 5, qi = row & 31;
      u16x8 vv = *(u16x8*)&ob[wreg * 2048 + qi * 64 +
                              ((j * 8) ^ ((qi & 7) << 3))];
      *(u16x8*)(Ow + ((long)(b * SN + q0 + row)) * DN + h * HD + j * 8) = vv;
    }
  } else {
    // ---- write fp32 partials: Op[c][bh][hd][S] (q-contiguous), m/l per q
    const long pb0 = (long)(c * 16 + bh) * 64;
#pragma unroll
    for (int oh = 0; oh < 2; ++oh)
#pragma unroll
      for (int rq = 0; rq < 4; ++rq)
#pragma unroll
        for (int e = 0; e < 4; ++e) {
          const int hd = 32 * oh + 8 * rq + 4 * h5 + e;
          Op[(pb0 + hd) * SN + qw + l31] = oacc[oh][4 * rq + e];
        }
    if (h5 == 0) {
      Mp[(long)(c * 16 + bh) * SN + qw + l31] = m_;
      Lp[(long)(c * 16 + bh) * SN + qw + l31] = l_;
    }
  }
}

// ---------------- merge NS split-KV partials -> bf16 Ow [B,S,D]
template <int NS>
__global__ __launch_bounds__(256) void merge_kernel(
    const float* __restrict__ Op, const float* __restrict__ Mp,
    const float* __restrict__ Lp, unsigned short* __restrict__ Ow) {
  __shared__ float wsm[NS][64];
  __shared__ __align__(16) unsigned short obuf[64][72];
  const int tid = threadIdx.x;
  const int bh = blockIdx.x >> 6;
  const int qb = (blockIdx.x & 63) * 64;
  if (tid < 64) {
    const int q = qb + tid;
    float m[NS], l[NS];
    float ms = -INFINITY;
#pragma unroll
    for (int i = 0; i < NS; ++i) {
      m[i] = Mp[(long)(i * 16 + bh) * SN + q];
      l[i] = Lp[(long)(i * 16 + bh) * SN + q];
      ms = fmaxf(ms, m[i]);
    }
    float denom = 0.f, a[NS];
#pragma unroll
    for (int i = 0; i < NS; ++i) {
      a[i] = __builtin_amdgcn_exp2f(m[i] - ms);
      denom += l[i] * a[i];
    }
    const float rl = 1.f / denom;
#pragma unroll
    for (int i = 0; i < NS; ++i) wsm[i][tid] = a[i] * rl;
  }
  __syncthreads();
#pragma unroll
  for (int pass = 0; pass < 16; ++pass) {
    const int idx = pass * 256 + tid;
    const int hd = idx >> 6, q = idx & 63;  // consecutive tid -> consecutive q
    float acc = 0.f;
#pragma unroll
    for (int i = 0; i < NS; ++i)
      acc += Op[((long)(i * 16 + bh) * 64 + hd) * SN + qb + q] * wsm[i][q];
    obuf[q][hd ^ ((q & 7) << 3)] = f2bf(acc);
  }
  __syncthreads();
  const int b = bh >> 2, h = bh & 3;
#pragma unroll
  for (int pass = 0; pass < 4; ++pass) {
    const int idx = pass * 256 + tid;
    const int q = idx >> 4, hg = (idx & 15) * 4;  // uint2 = 4 bf16
    uint2 v = *(uint2*)&obuf[q][hg ^ ((q & 7) << 3)];
    *(uint2*)(Ow + ((long)(b * SN + qb + q)) * DN + h * HD + hg) = v;
  }
}

extern "C" void kernel_launch(void* const* d_in, const int* in_sizes, int n_in,
                              void* d_out, int out_size, void* d_ws, size_t ws_size,
                              hipStream_t stream) {
  const float* x  = (const float*)d_in[0];
  const float* Wq = (const float*)d_in[1];
  const float* Wk = (const float*)d_in[2];
  const float* Wv = (const float*)d_in[3];
  const float* Wo = (const float*)d_in[4];
  float* out = (float*)d_out;

  const size_t per = (size_t)MROWS * DN;  // 4,194,304 ushorts
  unsigned short* xb   = (unsigned short*)d_ws;
  unsigned short* Wcat = xb + per;
  unsigned short* Wob  = Wcat + 768 * 256;
  unsigned short* Qw   = Wob + 65536;
  unsigned short* Kw   = Qw + per;
  unsigned short* VTw  = Kw + per;   // V^T [B,H,HD,S]
  unsigned short* Ow   = xb;         // alias: xb dead after qkv gemm
  const size_t base_bytes = (4 * per + 768 * 256 + 65536) * sizeof(unsigned short);
  float* Op = (float*)((char*)d_ws + base_bytes);      // [2][16][64][S] fp32
  float* Mp = Op + (size_t)2 * 16 * 64 * SN;           // [2][16][S]
  float* Lp = Mp + (size_t)2 * 16 * SN;
  const size_t need = base_bytes +
      ((size_t)2 * 16 * 64 * SN + 2 * (size_t)2 * 16 * SN) * sizeof(float);

  convert_kernel<<<2048, 256, 0, stream>>>(x, Wq, Wk, Wv, Wo, xb, Wcat, Wob);
  gemm_kernel<0, 6><<<6 * (MROWS / 128), 256, 0, stream>>>(
      xb, Wcat, Qw, Kw, VTw, nullptr);
  if (ws_size >= need) {
    attn_kernel<2><<<512, 512, 0, stream>>>(Qw, Kw, VTw, nullptr, Op, Mp, Lp);
    merge_kernel<2><<<16 * (SN / 64), 256, 0, stream>>>(Op, Mp, Lp, Ow);
  } else {
    attn_kernel<1><<<256, 512, 0, stream>>>(
        Qw, Kw, VTw, Ow, nullptr, nullptr, nullptr);
  }
  gemm_kernel<1, 2><<<2 * (MROWS / 128), 256, 0, stream>>>(
      Ow, Wob, nullptr, nullptr, nullptr, out);
}

// Round 17
// 91.730 us; speedup vs baseline: 1.4068x; 1.4068x over previous
//
#include <hip/hip_runtime.h>
#include <hip/hip_bf16.h>
#include <cstdint>

using short8  = __attribute__((ext_vector_type(8))) short;
using u16x8   = __attribute__((ext_vector_type(8))) unsigned short;
using u16x4   = __attribute__((ext_vector_type(4))) unsigned short;
using f32x4   = __attribute__((ext_vector_type(4))) float;
using f32x16  = __attribute__((ext_vector_type(16))) float;

constexpr int BN = 4, HN = 4, SN = 4096, DN = 256, HD = 64;
constexpr int MROWS = BN * SN;  // 16384
// Q pre-scale: (1/sqrt(64)) * log2(e) -> scores land in exp2 domain
constexpr float QSCL = 0.18033688011112042f;

__device__ __forceinline__ unsigned short f2bf(float x) {
  union { float f; unsigned int u; } c; c.f = x;
  unsigned int u = c.u;
  return (unsigned short)((u + 0x7fffu + ((u >> 16) & 1u)) >> 16);
}
__device__ __forceinline__ float bf2f(unsigned short h) {
  union { unsigned int u; float f; } c; c.u = ((unsigned int)h) << 16;
  return c.f;
}
__device__ __forceinline__ unsigned int cvt_pk_bf16(float a, float b) {
  unsigned int r;
  asm("v_cvt_pk_bf16_f32 %0, %1, %2" : "=v"(r) : "v"(a), "v"(b));
  return r;  // low16 = bf16(a), high16 = bf16(b)
}
// proven-correct since round 5: operands are distinct values produced by
// cvt_pk several instructions before the swap (hazard-safe by distance).
__device__ __forceinline__ void pl32swap(unsigned int& a, unsigned int& b) {
  asm volatile("v_permlane32_swap_b32 %0, %1" : "+v"(a), "+v"(b));
}

#define GLDS16(g, l)                                                  \
  __builtin_amdgcn_global_load_lds(                                   \
      (const __attribute__((address_space(1))) void*)(g),             \
      (__attribute__((address_space(3))) void*)(l), 16, 0, 0)

// ---------------- fp32 -> bf16 conversion: x, Wq|Wk|Wv (concat), Wo
__global__ __launch_bounds__(256) void convert_kernel(
    const float* __restrict__ x,  const float* __restrict__ Wq,
    const float* __restrict__ Wk, const float* __restrict__ Wv,
    const float* __restrict__ Wo,
    unsigned short* __restrict__ xb, unsigned short* __restrict__ Wcat,
    unsigned short* __restrict__ Wob) {
  const long NX4 = (long)MROWS * DN / 4;
  const long NW4 = 65536 / 4;
  const long total = NX4 + 4 * NW4;
  for (long i = (long)blockIdx.x * 256 + threadIdx.x; i < total;
       i += (long)gridDim.x * 256) {
    const float* src; unsigned short* dst;
    if (i < NX4) { src = x + i * 4; dst = xb + i * 4; }
    else {
      long j = i - NX4; int w = (int)(j >> 14); long o = (j & 16383) * 4;
      src = (w == 0 ? Wq : w == 1 ? Wk : w == 2 ? Wv : Wo) + o;
      dst = (w < 3 ? Wcat + (long)w * 65536 : Wob) + o;
    }
    float4 v = *(const float4*)src;
    u16x4 pk; pk[0] = f2bf(v.x); pk[1] = f2bf(v.y);
    pk[2] = f2bf(v.z); pk[3] = f2bf(v.w);
    *(u16x4*)dst = pk;
  }
}

// ---------------- bf16 MFMA GEMM: C[M][N] = A[M][K=256] * B[N][K=256]^T
// MODE 0: write q(*QSCL)/k bf16 [B,H,S,HD]; V transposed as [B,H,HD,S].
// MODE 1: write fp32 [M][256].
template <int MODE, int NBN>
__global__ __launch_bounds__(256) void gemm_kernel(
    const unsigned short* __restrict__ Abf,
    const unsigned short* __restrict__ Bbf,
    unsigned short* __restrict__ qo, unsigned short* __restrict__ ko,
    unsigned short* __restrict__ vo, float* __restrict__ out) {
  constexpr int SMEM = (MODE == 1) ? 128 * 132 * 4 : 128 * 136 * 2;
  __shared__ __align__(16) char smem[SMEM];
  unsigned short* stg = (unsigned short*)smem;

  const int tid = threadIdx.x, lane = tid & 63, wid = tid >> 6;
  const int lo = lane & 15, hi = lane >> 4;
  const int bn = blockIdx.x % NBN, bm = blockIdx.x / NBN;
  const int wm = (wid >> 1) * 64, wn = (wid & 1) * 64;
  const long arow0 = (long)bm * 128, brow0 = (long)bn * 128;

  auto stage = [&](int buf, int kt) {
    const int row = (wid * 2) * 16 + (lane >> 2);
    const int col = (lane & 3) * 8;
    const unsigned short* ga = Abf + (arow0 + row) * DN + kt * 32 + col;
    const unsigned short* gb = Bbf + (brow0 + row) * DN + kt * 32 + col;
    unsigned short* la = stg + buf * 8192 + wid * 1024;
    unsigned short* lb = la + 4096;
    GLDS16(ga, la);
    GLDS16(ga + 16 * DN, la + 512);
    GLDS16(gb, lb);
    GLDS16(gb + 16 * DN, lb + 512);
  };

  f32x4 acc[4][4];
#pragma unroll
  for (int a = 0; a < 4; ++a)
#pragma unroll
    for (int b = 0; b < 4; ++b)
#pragma unroll
      for (int e = 0; e < 4; ++e) acc[a][b][e] = 0.f;

  stage(0, 0);
#pragma unroll
  for (int kt = 0; kt < 8; ++kt) {
    const int buf = kt & 1;
    __syncthreads();
    if (kt < 7) stage(buf ^ 1, kt + 1);
    const unsigned short* sa = stg + buf * 8192;
    const unsigned short* sb = sa + 4096;
    short8 af[4], bf[4];
#pragma unroll
    for (int f = 0; f < 4; ++f) {
      af[f] = *(const short8*)(sa + (wm + f * 16 + lo) * 32 + hi * 8);
      bf[f] = *(const short8*)(sb + (wn + f * 16 + lo) * 32 + hi * 8);
    }
#pragma unroll
    for (int fn = 0; fn < 4; ++fn)
#pragma unroll
      for (int fm = 0; fm < 4; ++fm)
        acc[fn][fm] = __builtin_amdgcn_mfma_f32_16x16x32_bf16(
            bf[fn], af[fm], acc[fn][fm], 0, 0, 0);
  }
  __syncthreads();

  if constexpr (MODE == 0) {
    unsigned short* cs = (unsigned short*)smem;
    if (bn < 4) {  // Q and K: [B,H,S,HD]
      const float cscl = (bn < 2) ? QSCL : 1.0f;
#pragma unroll
      for (int fn = 0; fn < 4; ++fn)
#pragma unroll
        for (int fm = 0; fm < 4; ++fm) {
          u16x4 pk;
#pragma unroll
          for (int r = 0; r < 4; ++r) pk[r] = f2bf(acc[fn][fm][r] * cscl);
          const int m = wm + fm * 16 + lo, n0 = wn + fn * 16 + hi * 4;
          *(u16x4*)(cs + m * 136 + n0) = pk;
        }
      __syncthreads();
      unsigned short* dstmat = (bn < 2) ? qo : ko;
      const int colbase = (bn & 1) * 128;
#pragma unroll
      for (int p = 0; p < 8; ++p) {
        const int ml = p * 16 + (tid >> 4), n0 = (tid & 15) * 8;
        u16x8 v = *(u16x8*)(cs + ml * 136 + n0);
        const int c = colbase + n0, h = c >> 6, hd = c & 63;
        const long m = arow0 + ml;
        const int b = (int)(m >> 12), s = (int)(m & 4095);
        *(u16x8*)(dstmat + ((long)(b * HN + h) * SN + s) * HD + hd) = v;
      }
    } else {  // V: store cs transposed, write V^T [B,H,HD,S]
#pragma unroll
      for (int fn = 0; fn < 4; ++fn)
#pragma unroll
        for (int fm = 0; fm < 4; ++fm) {
          const int m = wm + fm * 16 + lo, n0 = wn + fn * 16 + hi * 4;
#pragma unroll
          for (int r = 0; r < 4; ++r)
            cs[(n0 + r) * 136 + m] = f2bf(acc[fn][fm][r]);
        }
      __syncthreads();
      const int b = (int)(arow0 >> 12), sbase = (int)(arow0 & 4095);
#pragma unroll
      for (int p = 0; p < 8; ++p) {
        const int cl = p * 16 + (tid >> 4);   // local col (head-dim axis)
        const int s0 = (tid & 15) * 8;        // s offset within tile
        u16x8 v = *(u16x8*)(cs + cl * 136 + s0);
        const int c = (bn & 1) * 128 + cl, h = c >> 6, hd = c & 63;
        *(u16x8*)(vo + ((long)((b * HN + h) * HD + hd)) * SN + sbase + s0) = v;
      }
    }
  } else {
    float* csf = (float*)smem;
#pragma unroll
    for (int fn = 0; fn < 4; ++fn)
#pragma unroll
      for (int fm = 0; fm < 4; ++fm) {
        const int m = wm + fm * 16 + lo, n0 = wn + fn * 16 + hi * 4;
        *(f32x4*)(csf + m * 132 + n0) = acc[fn][fm];
      }
    __syncthreads();
#pragma unroll
    for (int p = 0; p < 8; ++p) {
      const int ml = p * 16 + (tid >> 4), n0 = (tid & 15) * 8;
      f32x4 v0 = *(f32x4*)(csf + ml * 132 + n0);
      f32x4 v1 = *(f32x4*)(csf + ml * 132 + n0 + 4);
      float* dst = out + (arow0 + ml) * DN + bn * 128 + n0;
      *(f32x4*)dst = v0;
      *(f32x4*)(dst + 4) = v1;
    }
  }
}

// ---------------- flash attention, causal. 4-warp blocks, 128 q rows
// (warp w owns q [qw, qw+32)). Exact round-13 structure (best measured:
// 58 us): K tile [64key][64hd] + V^T tile [64hd][64key] staged to LDS via
// global_load_lds, 16B XOR swizzle (inverse-swizzled global source +
// swizzled LDS reads), 2-phase pipeline with prologue barrier.
// Round-17 delta: split-KV partials stored as BF16 (halves Op traffic;
// Mp/Lp stay fp32 to keep -inf/l exact for empty parity chunks).
template <int NSPLIT>
__global__ __launch_bounds__(256, 2) void attn_kernel(
    const unsigned short* __restrict__ Qw, const unsigned short* __restrict__ Kw,
    const unsigned short* __restrict__ VTp, unsigned short* __restrict__ Ow,
    unsigned short* __restrict__ Op, float* __restrict__ Mp,
    float* __restrict__ Lp) {
  __shared__ __align__(16) unsigned short sK[2][4096];  // [key][hd] swz
  __shared__ __align__(16) unsigned short sV[2][4096];  // [hd][key] swz

  const int tid = threadIdx.x;
  const int w = tid >> 6, lane = tid & 63;
  const int l31 = lane & 31, h5 = lane >> 5;
  const int bid = blockIdx.x;
  const int bh = (bid & 7) * 2 + ((bid >> 3) & 1);
  int c, g;
  if constexpr (NSPLIT == 2) { c = (bid >> 4) & 1; g = bid >> 5; }
  else { c = 0; g = bid >> 4; }
  const int t = 31 - g;                    // heavy q-tiles first
  const int q0 = t * 128;
  const int qw = q0 + w * 32;
  const long base = (long)bh * SN * HD;    // == bh * HD * SN for V^T too
  const int tlast = 2 * t + 1;             // last kt tile for the block
  const int wlast = 2 * t + (w >> 1);      // this warp's last active tile

  // staging geometry: 8 issues of 1KB cover 64 rows x 128B; this wave's
  // two issues cover rows [w*16, w*16+8) and [w*16+8, +8).
  const int sr = w * 16 + (lane >> 3);          // row of this lane, issue 0
  const int gcol8 = (((lane & 7) ^ (lane >> 3)) << 3);  // inv-swizzled chunk
  auto stage = [&](int buf, int k0) {
    const unsigned short* gk = Kw + base + (long)(k0 + sr) * HD + gcol8;
    GLDS16(gk, &sK[buf][w * 1024]);
    GLDS16(gk + 8 * HD, &sK[buf][w * 1024 + 512]);
    const unsigned short* gv = VTp + base + (long)sr * SN + k0 + gcol8;
    GLDS16(gv, &sV[buf][w * 1024]);
    GLDS16(gv + 8 * SN, &sV[buf][w * 1024 + 512]);
  };

  // Q frags (B-operand): lane holds Q[qw+l31][16ks + 8*h5 + j], pre-scaled
  short8 qf[4];
#pragma unroll
  for (int ks = 0; ks < 4; ++ks)
    qf[ks] = *(const short8*)(Qw + base + (long)(qw + l31) * HD + ks * 16 + h5 * 8);

  f32x16 oacc[2];  // [oh]: O[hd=32*oh+crow(r,h5)][q=l31]
#pragma unroll
  for (int oh = 0; oh < 2; ++oh)
#pragma unroll
    for (int r = 0; r < 16; ++r) oacc[oh][r] = 0.f;
  float m_ = -INFINITY, l_ = 0.f;  // per-lane softmax state for q = qw+l31

  const int swz = (l31 & 7) << 3;  // read-side swizzle (ushort units /8)

  stage(0, c * 64);
  __syncthreads();  // drain prologue stage before first ds_read (r13 fix)
  int buf = 0;
  for (int kt = c; kt <= tlast; kt += NSPLIT) {
    if (kt + NSPLIT <= tlast) stage(buf ^ 1, (kt + NSPLIT) * 64);

    if (kt <= wlast) {
      const int k0 = kt * 64;
      // ---- K frags from LDS (swizzled, conflict-minimal b128)
      short8 kb[8];
#pragma unroll
      for (int s = 0; s < 2; ++s)
#pragma unroll
        for (int ks = 0; ks < 4; ++ks)
          kb[s * 4 + ks] = *(const short8*)&sK[buf][(32 * s + l31) * 64 +
                                                   (((2 * ks + h5) << 3) ^ swz)];
      // ---- QK^T: C[key=32s+crow(r,h5)][q=l31], log2 domain
      f32x16 c0, c1;
#pragma unroll
      for (int r = 0; r < 16; ++r) { c0[r] = 0.f; c1[r] = 0.f; }
#pragma unroll
      for (int ks = 0; ks < 4; ++ks)
        c0 = __builtin_amdgcn_mfma_f32_32x32x16_bf16(kb[ks], qf[ks], c0, 0, 0, 0);
#pragma unroll
      for (int ks = 0; ks < 4; ++ks)
        c1 = __builtin_amdgcn_mfma_f32_32x32x16_bf16(kb[4 + ks], qf[ks], c1, 0, 0, 0);

      // ---- V^T frags from LDS; latency hides under softmax below
      short8 vt0[4], vt1[4];
#pragma unroll
      for (int ks = 0; ks < 4; ++ks) {
        const int col = ((2 * ks + h5) << 3) ^ swz;
        vt0[ks] = *(const short8*)&sV[buf][l31 * 64 + col];
        vt1[ks] = *(const short8*)&sV[buf][(32 + l31) * 64 + col];
      }

      // ---- causal mask (only this warp's diagonal tile)
      if (kt == wlast) {
        const int mb0 = k0 + 4 * h5 - qw - l31;  // key - q for s=0, r=0
#pragma unroll
        for (int r = 0; r < 16; ++r) {
          const int d = (r & 3) + 8 * (r >> 2);
          if (mb0 + d > 0)      c0[r] = -INFINITY;
          if (mb0 + 32 + d > 0) c1[r] = -INFINITY;
        }
      }

      // ---- row max: in-reg tree + shfl cross-half
      float mv[16];
#pragma unroll
      for (int r = 0; r < 16; ++r) mv[r] = fmaxf(c0[r], c1[r]);
#pragma unroll
      for (int st = 8; st >= 1; st >>= 1)
#pragma unroll
        for (int i = 0; i < st; ++i) mv[i] = fmaxf(mv[i], mv[i + st]);
      const float mx = fmaxf(mv[0], __shfl_xor(mv[0], 32, 64));

      // ---- defer-max (T13): rescale only when max grew materially
      if (__any(mx > m_ + 11.5f)) {
        const float mn = fmaxf(m_, mx);
        const float alpha = __builtin_amdgcn_exp2f(m_ - mn);
        m_ = mn;
        l_ *= alpha;
#pragma unroll
        for (int oh = 0; oh < 2; ++oh)
#pragma unroll
          for (int r = 0; r < 16; ++r) oacc[oh][r] *= alpha;
      }

      // ---- exp2 + row sum
#pragma unroll
      for (int r = 0; r < 16; ++r) {
        c0[r] = __builtin_amdgcn_exp2f(c0[r] - m_);
        c1[r] = __builtin_amdgcn_exp2f(c1[r] - m_);
      }
      float sv[16];
#pragma unroll
      for (int r = 0; r < 16; ++r) sv[r] = c0[r] + c1[r];
#pragma unroll
      for (int st = 8; st >= 1; st >>= 1)
#pragma unroll
        for (int i = 0; i < st; ++i) sv[i] += sv[i + st];
      l_ += sv[0] + __shfl_xor(sv[0], 32, 64);

      // ---- P (B-operand) in-register via cvt_pk + permlane32_swap (T12)
      short8 pb[4];
#pragma unroll
      for (int s = 0; s < 2; ++s)
#pragma unroll
        for (int u = 0; u < 2; ++u) {
          unsigned int a0, a1, b0, b1;
          if (s == 0) {
            a0 = cvt_pk_bf16(c0[8 * u + 0], c0[8 * u + 1]);
            a1 = cvt_pk_bf16(c0[8 * u + 2], c0[8 * u + 3]);
            b0 = cvt_pk_bf16(c0[8 * u + 4], c0[8 * u + 5]);
            b1 = cvt_pk_bf16(c0[8 * u + 6], c0[8 * u + 7]);
          } else {
            a0 = cvt_pk_bf16(c1[8 * u + 0], c1[8 * u + 1]);
            a1 = cvt_pk_bf16(c1[8 * u + 2], c1[8 * u + 3]);
            b0 = cvt_pk_bf16(c1[8 * u + 4], c1[8 * u + 5]);
            b1 = cvt_pk_bf16(c1[8 * u + 6], c1[8 * u + 7]);
          }
          pl32swap(a0, b0);
          pl32swap(a1, b1);
          union { unsigned int u4[4]; short8 v; } pu;
          pu.u4[0] = a0; pu.u4[1] = a1; pu.u4[2] = b0; pu.u4[3] = b1;
          pb[s * 2 + u] = pu.v;
        }

      // ---- PV: oacc[oh] += V^T * P
#pragma unroll
      for (int ks = 0; ks < 4; ++ks) {
        oacc[0] = __builtin_amdgcn_mfma_f32_32x32x16_bf16(vt0[ks], pb[ks], oacc[0], 0, 0, 0);
        oacc[1] = __builtin_amdgcn_mfma_f32_32x32x16_bf16(vt1[ks], pb[ks], oacc[1], 0, 0, 0);
      }
    }

    __syncthreads();  // drains this iter's staged loads; fences buf reuse
    buf ^= 1;
  }

  if constexpr (NSPLIT == 1) {
    // ---- epilogue: transpose O through LDS (reuse sK) for coalesced store
    unsigned short* ob = (unsigned short*)sK;  // 4 warps x [32 q][64 hd]
    const float rl = 1.f / l_;
#pragma unroll
    for (int oh = 0; oh < 2; ++oh)
#pragma unroll
      for (int rq = 0; rq < 4; ++rq) {
        const int hdb = 32 * oh + 8 * rq + 4 * h5;
        const unsigned int u0 = cvt_pk_bf16(oacc[oh][4 * rq + 0] * rl,
                                            oacc[oh][4 * rq + 1] * rl);
        const unsigned int u1 = cvt_pk_bf16(oacc[oh][4 * rq + 2] * rl,
                                            oacc[oh][4 * rq + 3] * rl);
        *(uint2*)&ob[w * 2048 + l31 * 64 + (hdb ^ ((l31 & 7) << 3))] =
            make_uint2(u0, u1);
      }
    __syncthreads();
    const int b = bh >> 2, h = bh & 3;
#pragma unroll
    for (int pass = 0; pass < 4; ++pass) {
      const int idx = pass * 256 + tid;
      const int row = idx >> 3, j = idx & 7;    // row 0..127, 8 ushorts
      const int wreg = row >> 5, qi = row & 31;
      u16x8 vv = *(u16x8*)&ob[wreg * 2048 + qi * 64 +
                              ((j * 8) ^ ((qi & 7) << 3))];
      *(u16x8*)(Ow + ((long)(b * SN + q0 + row)) * DN + h * HD + j * 8) = vv;
    }
  } else {
    // ---- write bf16 partials: Op[c][bh][hd][S] (q-contiguous), m/l fp32
    const long pb0 = (long)(c * 16 + bh) * 64;
#pragma unroll
    for (int oh = 0; oh < 2; ++oh)
#pragma unroll
      for (int rq = 0; rq < 4; ++rq)
#pragma unroll
        for (int e = 0; e < 4; ++e) {
          const int hd = 32 * oh + 8 * rq + 4 * h5 + e;
          Op[(pb0 + hd) * SN + qw + l31] = f2bf(oacc[oh][4 * rq + e]);
        }
    if (h5 == 0) {
      Mp[(long)(c * 16 + bh) * SN + qw + l31] = m_;
      Lp[(long)(c * 16 + bh) * SN + qw + l31] = l_;
    }
  }
}

// ---------------- merge NS split-KV bf16 partials -> bf16 Ow [B,S,D]
template <int NS>
__global__ __launch_bounds__(256) void merge_kernel(
    const unsigned short* __restrict__ Op, const float* __restrict__ Mp,
    const float* __restrict__ Lp, unsigned short* __restrict__ Ow) {
  __shared__ float wsm[NS][64];
  __shared__ __align__(16) unsigned short obuf[64][72];
  const int tid = threadIdx.x;
  const int bh = blockIdx.x >> 6;
  const int qb = (blockIdx.x & 63) * 64;
  if (tid < 64) {
    const int q = qb + tid;
    float m[NS], l[NS];
    float ms = -INFINITY;
#pragma unroll
    for (int i = 0; i < NS; ++i) {
      m[i] = Mp[(long)(i * 16 + bh) * SN + q];
      l[i] = Lp[(long)(i * 16 + bh) * SN + q];
      ms = fmaxf(ms, m[i]);
    }
    float denom = 0.f, a[NS];
#pragma unroll
    for (int i = 0; i < NS; ++i) {
      a[i] = __builtin_amdgcn_exp2f(m[i] - ms);
      denom += l[i] * a[i];
    }
    const float rl = 1.f / denom;
#pragma unroll
    for (int i = 0; i < NS; ++i) wsm[i][tid] = a[i] * rl;
  }
  __syncthreads();
#pragma unroll
  for (int pass = 0; pass < 16; ++pass) {
    const int idx = pass * 256 + tid;
    const int hd = idx >> 6, q = idx & 63;  // consecutive tid -> consecutive q
    float acc = 0.f;
#pragma unroll
    for (int i = 0; i < NS; ++i)
      acc += bf2f(Op[((long)(i * 16 + bh) * 64 + hd) * SN + qb + q]) * wsm[i][q];
    obuf[q][hd ^ ((q & 7) << 3)] = f2bf(acc);
  }
  __syncthreads();
  const int b = bh >> 2, h = bh & 3;
#pragma unroll
  for (int pass = 0; pass < 4; ++pass) {
    const int idx = pass * 256 + tid;
    const int q = idx >> 4, hg = (idx & 15) * 4;  // uint2 = 4 bf16
    uint2 v = *(uint2*)&obuf[q][hg ^ ((q & 7) << 3)];
    *(uint2*)(Ow + ((long)(b * SN + qb + q)) * DN + h * HD + hg) = v;
  }
}

extern "C" void kernel_launch(void* const* d_in, const int* in_sizes, int n_in,
                              void* d_out, int out_size, void* d_ws, size_t ws_size,
                              hipStream_t stream) {
  const float* x  = (const float*)d_in[0];
  const float* Wq = (const float*)d_in[1];
  const float* Wk = (const float*)d_in[2];
  const float* Wv = (const float*)d_in[3];
  const float* Wo = (const float*)d_in[4];
  float* out = (float*)d_out;

  const size_t per = (size_t)MROWS * DN;  // 4,194,304 ushorts
  unsigned short* xb   = (unsigned short*)d_ws;
  unsigned short* Wcat = xb + per;
  unsigned short* Wob  = Wcat + 768 * 256;
  unsigned short* Qw   = Wob + 65536;
  unsigned short* Kw   = Qw + per;
  unsigned short* VTw  = Kw + per;   // V^T [B,H,HD,S]
  unsigned short* Ow   = xb;         // alias: xb dead after qkv gemm
  const size_t base_bytes = (4 * per + 768 * 256 + 65536) * sizeof(unsigned short);
  unsigned short* Op = (unsigned short*)((char*)d_ws + base_bytes);  // [2][16][64][S] bf16
  float* Mp = (float*)(Op + (size_t)2 * 16 * 64 * SN);               // [2][16][S] fp32
  float* Lp = Mp + (size_t)2 * 16 * SN;
  const size_t need = base_bytes +
      (size_t)2 * 16 * 64 * SN * sizeof(unsigned short) +
      2 * (size_t)2 * 16 * SN * sizeof(float);

  convert_kernel<<<2048, 256, 0, stream>>>(x, Wq, Wk, Wv, Wo, xb, Wcat, Wob);
  gemm_kernel<0, 6><<<6 * (MROWS / 128), 256, 0, stream>>>(
      xb, Wcat, Qw, Kw, VTw, nullptr);
  if (ws_size >= need) {
    attn_kernel<2><<<1024, 256, 0, stream>>>(Qw, Kw, VTw, nullptr, Op, Mp, Lp);
    merge_kernel<2><<<16 * (SN / 64), 256, 0, stream>>>(Op, Mp, Lp, Ow);
  } else {
    attn_kernel<1><<<512, 256, 0, stream>>>(
        Qw, Kw, VTw, Ow, nullptr, nullptr, nullptr);
  }
  gemm_kernel<1, 2><<<2 * (MROWS / 128), 256, 0, stream>>>(
      Ow, Wob, nullptr, nullptr, nullptr, out);
}